// Round 1
// baseline (297.318 us; speedup 1.0000x reference)
//
#include <hip/hip_runtime.h>

// BackWarp: dense_image_warp (bilinear, edge-clamped), B=32, H=512, W=512, C=4.
// out[b,i,j,:] = bilinear(image[b], (i - flow[b,i,j,0], j - flow[b,i,j,1]))
// floor clamped to [0, size-2], alpha clamped to [0,1] (tfa semantics).

#define BW_B 32
#define BW_H 512
#define BW_W 512
// C = 4 floats = one float4 per pixel.

__global__ __launch_bounds__(256) void backwarp_kernel(
    const float* __restrict__ image,   // [B,H,W,4]
    const float* __restrict__ flow,    // [B,H,W,2]
    float* __restrict__ out)           // [B,H,W,4]
{
    const long long idx = (long long)blockIdx.x * blockDim.x + threadIdx.x;
    // total pixels = B*H*W = 2^23; grid sized exactly, no bounds check needed,
    // but keep a guard for safety.
    if (idx >= (long long)BW_B * BW_H * BW_W) return;

    const int j = (int)(idx & (BW_W - 1));          // W = 512 = 2^9
    const int i = (int)((idx >> 9) & (BW_H - 1));   // H = 512 = 2^9
    const int b = (int)(idx >> 18);

    const float2 f = *reinterpret_cast<const float2*>(flow + idx * 2);
    const float qy = (float)i - f.x;
    const float qx = (float)j - f.y;

    float fy = floorf(qy);
    float fx = floorf(qx);
    fy = fminf(fmaxf(fy, 0.0f), (float)(BW_H - 2));
    fx = fminf(fmaxf(fx, 0.0f), (float)(BW_W - 2));
    const float ay = fminf(fmaxf(qy - fy, 0.0f), 1.0f);
    const float ax = fminf(fmaxf(qx - fx, 0.0f), 1.0f);
    const int iy = (int)fy;
    const int ix = (int)fx;

    const float4* __restrict__ img4 = reinterpret_cast<const float4*>(image);
    const long long base = ((long long)b * BW_H + iy) * BW_W + ix;

    const float4 tl = img4[base];
    const float4 tr = img4[base + 1];
    const float4 bl = img4[base + BW_W];
    const float4 br = img4[base + BW_W + 1];

    float4 r;
    {
        const float tx = tl.x + ax * (tr.x - tl.x);
        const float bx = bl.x + ax * (br.x - bl.x);
        r.x = tx + ay * (bx - tx);
    }
    {
        const float ty = tl.y + ax * (tr.y - tl.y);
        const float by = bl.y + ax * (br.y - bl.y);
        r.y = ty + ay * (by - ty);
    }
    {
        const float tz = tl.z + ax * (tr.z - tl.z);
        const float bz = bl.z + ax * (br.z - bl.z);
        r.z = tz + ay * (bz - tz);
    }
    {
        const float tw = tl.w + ax * (tr.w - tl.w);
        const float bw = bl.w + ax * (br.w - bl.w);
        r.w = tw + ay * (bw - tw);
    }

    reinterpret_cast<float4*>(out)[idx] = r;
}

extern "C" void kernel_launch(void* const* d_in, const int* in_sizes, int n_in,
                              void* d_out, int out_size, void* d_ws, size_t ws_size,
                              hipStream_t stream) {
    const float* image = (const float*)d_in[0];
    const float* flow  = (const float*)d_in[1];
    float* out = (float*)d_out;

    const long long total = (long long)BW_B * BW_H * BW_W;   // 8,388,608 pixels
    const int block = 256;
    const long long grid = (total + block - 1) / block;       // 32768 blocks

    backwarp_kernel<<<(unsigned)grid, block, 0, stream>>>(image, flow, out);
}